// Round 1
// baseline (644.669 us; speedup 1.0000x reference)
//
#include <hip/hip_runtime.h>

// ---------------------------------------------------------------------------
// Shifted Window Attention, fully fused per-window. bf16 MFMA 16x16x32.
// C=192, H=W=448, window 7x7 (N=49 pad 64), shift 3, NH=6, hd=32, nW=4096.
// ---------------------------------------------------------------------------

typedef short s16x8 __attribute__((ext_vector_type(8)));   // 8 bf16 (4 VGPRs)
typedef float f32x4 __attribute__((ext_vector_type(4)));
typedef unsigned short u16x4 __attribute__((ext_vector_type(4)));

#define C_DIM 192
#define H_DIM 448
#define W_DIM 448
#define HW    (H_DIM * W_DIM)   // 200704
#define NHEAD 6
#define NTOK  49
#define MT    64                // padded token count

// LDS strides in bf16 elements (chosen: 16B-aligned rows, <=2-way bank alias)
#define XW_S 200
#define AO_S 200
#define QH_S 40
#define KH_S 40
#define VT_S 72
#define PH_S 72

__device__ __forceinline__ unsigned short f2bf(float f) {
  unsigned u = __float_as_uint(f);
  u = (u + 0x7fffu + ((u >> 16) & 1u)) >> 16;   // RNE
  return (unsigned short)u;
}

// ---- prep: pack qkv_weight (576x192 f32) into B-fragment order, bf16 -------
// layout: g = ((((h*3+which)*2+dt)*6+kk)*64+lane), 8 bf16 per g
// value j: W[n][kb+j], n = which*192 + h*32 + dt*16 + (lane%16),
//          kb = kk*32 + (lane/16)*8
__global__ void pack_wqkv(const float* __restrict__ w, unsigned short* __restrict__ dst) {
  int g = blockIdx.x * blockDim.x + threadIdx.x;
  if (g >= 13824) return;
  int lane = g & 63;
  int t1 = g >> 6;
  int kk = t1 % 6;  t1 /= 6;
  int dt = t1 & 1;  t1 >>= 1;
  int which = t1 % 3;
  int h = t1 / 3;
  int n  = which * 192 + h * 32 + dt * 16 + (lane & 15);
  int kb = kk * 32 + (lane >> 4) * 8;
  const float* src = w + n * 192 + kb;
  unsigned short* d = dst + g * 8;
#pragma unroll
  for (int j = 0; j < 8; j++) d[j] = f2bf(src[j]);
}

// ---- prep: pack proj_weight (192x192) -------------------------------------
// g = ((nt*6+kk)*64+lane); value j: W[n][kb+j], n = nt*16+(lane%16)
__global__ void pack_wproj(const float* __restrict__ w, unsigned short* __restrict__ dst) {
  int g = blockIdx.x * blockDim.x + threadIdx.x;
  if (g >= 4608) return;
  int lane = g & 63;
  int t1 = g >> 6;
  int kk = t1 % 6;
  int nt = t1 / 6;
  int n  = nt * 16 + (lane & 15);
  int kb = kk * 32 + (lane >> 4) * 8;
  const float* src = w + n * 192 + kb;
  unsigned short* d = dst + g * 8;
#pragma unroll
  for (int j = 0; j < 8; j++) d[j] = f2bf(src[j]);
}

// ---- prep: relative-position bias -> [6][64][64] f32, zero-padded ---------
// Faithful to reference quirk: idx = (ri-rj)+(ci-cj) in [-12,12], negative
// wraps (python indexing) -> +169.
__global__ void bias_prep(const float* __restrict__ table, float* __restrict__ dst) {
  int t = blockIdx.x * blockDim.x + threadIdx.x;
  if (t >= 6 * 64 * 64) return;
  int j = t & 63;
  int i = (t >> 6) & 63;
  int h = t >> 12;
  float v = 0.f;
  if (i < NTOK && j < NTOK) {
    int s = (i / 7 - j / 7) + (i % 7 - j % 7);
    if (s < 0) s += 169;
    v = table[s * 6 + h];
  }
  dst[t] = v;
}

// ---------------------------------------------------------------------------
__global__ __launch_bounds__(256, 2) void swin_fused(
    const float* __restrict__ x,
    const float* __restrict__ qkv_bias,
    const float* __restrict__ proj_bias,
    const unsigned short* __restrict__ wqkv_p,
    const unsigned short* __restrict__ wproj_p,
    const float* __restrict__ biasM,     // [6][64][64] f32
    float* __restrict__ out) {
  __shared__ __align__(16) unsigned short xw[MT * XW_S];   // tokens x C (bf16)
  __shared__ __align__(16) unsigned short ao[MT * AO_S];   // attn out tokens x C
  __shared__ __align__(16) unsigned short qh[MT * QH_S];   // per-head q 64x32
  __shared__ __align__(16) unsigned short kh[MT * KH_S];   // per-head k 64x32
  __shared__ __align__(16) unsigned short vth[32 * VT_S];  // per-head v^T 32x64
  __shared__ __align__(16) unsigned short Ph[MT * PH_S];   // per-head P 64x64
  __shared__ int mreg[MT];

  const int tid  = threadIdx.x;
  const int lane = tid & 63;
  const int wid  = tid >> 6;
  const int l16  = lane & 15;
  const int quad = lane >> 4;
  const int wr   = blockIdx.x >> 6;
  const int wc   = blockIdx.x & 63;

  // ---- Phase 0: stage rolled window into LDS (bf16), zero pad rows -------
  for (int task = tid; task < 1344; task += 256) {      // (c,i) pairs: 192*7
    int c = task / 7;
    int i = task % 7;
    int r = wr * 7 + i + 3; if (r >= H_DIM) r -= H_DIM;
    const float* src = x + c * HW + r * W_DIM;
    int cb = wc * 7 + 3;
#pragma unroll
    for (int j = 0; j < 7; j++) {
      int w = cb + j; if (w >= W_DIM) w -= W_DIM;
      xw[(i * 7 + j) * XW_S + c] = f2bf(src[w]);
    }
  }
  for (int idx = tid; idx < 15 * C_DIM; idx += 256)     // zero rows 49..63
    xw[(NTOK + idx / C_DIM) * XW_S + (idx % C_DIM)] = 0;
  if (tid < MT) {
    int v = 99;                                          // distinct for pads
    if (tid < NTOK) {
      int gi = wr * 7 + tid / 7, gj = wc * 7 + tid % 7;
      int rb = (gi >= 441) + (gi >= 445);
      int cb = (gj >= 441) + (gj >= 445);
      v = rb * 3 + cb;
    }
    mreg[tid] = v;
  }
  __syncthreads();

  const float scale = 0.17677669529663687f;   // 32^-0.5

  for (int h = 0; h < NHEAD; h++) {
    // ---- H1: per-head qkv chunk gemm (64x96, K=192) ----------------------
    // 6 n-tiles (q0,q1,k0,k1,v0,v1); wave w owns e=w, e=w+4
    for (int e = wid; e < 6; e += 4) {
      int which = e >> 1;   // 0=q 1=k 2=v
      int dt = e & 1;
      s16x8 bf[6];
      const s16x8* wp = (const s16x8*)wqkv_p;
      int base = (((h * 3 + which) * 2 + dt) * 6) * 64 + lane;
#pragma unroll
      for (int kk = 0; kk < 6; kk++) bf[kk] = wp[base + kk * 64];
      int ncol = which * 192 + h * 32 + dt * 16 + l16;
      float bias = qkv_bias[ncol];
      int dl = dt * 16 + l16;
#pragma unroll
      for (int mt = 0; mt < 4; mt++) {
        f32x4 acc = {0.f, 0.f, 0.f, 0.f};
#pragma unroll
        for (int kk = 0; kk < 6; kk++) {
          s16x8 a = *(const s16x8*)&xw[(mt * 16 + l16) * XW_S + kk * 32 + quad * 8];
          acc = __builtin_amdgcn_mfma_f32_16x16x32_bf16(a, bf[kk], acc, 0, 0, 0);
        }
        int t0 = mt * 16 + quad * 4;
        if (which == 0) {
#pragma unroll
          for (int r = 0; r < 4; r++) qh[(t0 + r) * QH_S + dl] = f2bf(acc[r] + bias);
        } else if (which == 1) {
#pragma unroll
          for (int r = 0; r < 4; r++) kh[(t0 + r) * KH_S + dl] = f2bf(acc[r] + bias);
        } else {
          u16x4 pv;
#pragma unroll
          for (int r = 0; r < 4; r++) pv[r] = f2bf(acc[r] + bias);
          *(u16x4*)&vth[dl * VT_S + t0] = pv;        // transposed store
        }
      }
    }
    __syncthreads();

    // ---- H2: scores + softmax (wave owns m-tile = wid) -------------------
    {
      const int mt = wid;
      s16x8 aq = *(const s16x8*)&qh[(mt * 16 + l16) * QH_S + quad * 8];
      f32x4 sc[4];
#pragma unroll
      for (int nt = 0; nt < 4; nt++) {
        s16x8 bk = *(const s16x8*)&kh[(nt * 16 + l16) * KH_S + quad * 8];
        f32x4 z = {0.f, 0.f, 0.f, 0.f};
        sc[nt] = __builtin_amdgcn_mfma_f32_16x16x32_bf16(aq, bk, z, 0, 0, 0);
      }
      float sv[4][4];   // [r][nt]
#pragma unroll
      for (int nt = 0; nt < 4; nt++) {
        int j = nt * 16 + l16;
        int mj = mreg[j];
        float mpad = (j >= NTOK) ? -30000.f : 0.f;
#pragma unroll
        for (int r = 0; r < 4; r++) {
          int i = mt * 16 + quad * 4 + r;
          float s = sc[nt][r] * scale + biasM[(h * 64 + i) * 64 + j];
          s += (mreg[i] == mj) ? 0.f : -100.f;
          sv[r][nt] = s + mpad;
        }
      }
#pragma unroll
      for (int r = 0; r < 4; r++) {
        float mx = fmaxf(fmaxf(sv[r][0], sv[r][1]), fmaxf(sv[r][2], sv[r][3]));
#pragma unroll
        for (int off = 1; off < 16; off <<= 1) mx = fmaxf(mx, __shfl_xor(mx, off));
        float e0 = __expf(sv[r][0] - mx), e1 = __expf(sv[r][1] - mx);
        float e2 = __expf(sv[r][2] - mx), e3 = __expf(sv[r][3] - mx);
        float sm = e0 + e1 + e2 + e3;
#pragma unroll
        for (int off = 1; off < 16; off <<= 1) sm += __shfl_xor(sm, off);
        float inv = 1.f / sm;
        int i = mt * 16 + quad * 4 + r;
        Ph[i * PH_S +  0 + l16] = f2bf(e0 * inv);
        Ph[i * PH_S + 16 + l16] = f2bf(e1 * inv);
        Ph[i * PH_S + 32 + l16] = f2bf(e2 * inv);
        Ph[i * PH_S + 48 + l16] = f2bf(e3 * inv);
      }
    }
    // No barrier needed: wave w wrote Ph rows [w*16,w*16+16) and reads only
    // those same rows below; vth was covered by the H1 barrier.

    // ---- H3: PV (wave owns m-tile = wid) ---------------------------------
    {
      const int mt = wid;
      s16x8 ap0 = *(const s16x8*)&Ph[(mt * 16 + l16) * PH_S + quad * 8];
      s16x8 ap1 = *(const s16x8*)&Ph[(mt * 16 + l16) * PH_S + 32 + quad * 8];
#pragma unroll
      for (int dtv = 0; dtv < 2; dtv++) {
        s16x8 bv0 = *(const s16x8*)&vth[(dtv * 16 + l16) * VT_S + quad * 8];
        s16x8 bv1 = *(const s16x8*)&vth[(dtv * 16 + l16) * VT_S + 32 + quad * 8];
        f32x4 acc = {0.f, 0.f, 0.f, 0.f};
        acc = __builtin_amdgcn_mfma_f32_16x16x32_bf16(ap0, bv0, acc, 0, 0, 0);
        acc = __builtin_amdgcn_mfma_f32_16x16x32_bf16(ap1, bv1, acc, 0, 0, 0);
        int t0 = mt * 16 + quad * 4;
#pragma unroll
        for (int r = 0; r < 4; r++)
          ao[(t0 + r) * AO_S + h * 32 + dtv * 16 + l16] = f2bf(acc[r]);
      }
    }
    __syncthreads();   // protects qh/kh/vth reuse next head, ao for proj
  }

  // ---- Proj (64x192, K=192) + un-roll scatter store -----------------------
  for (int nt = wid; nt < 12; nt += 4) {
    s16x8 bf[6];
    const s16x8* wp = (const s16x8*)wproj_p;
    int base = nt * 6 * 64 + lane;
#pragma unroll
    for (int kk = 0; kk < 6; kk++) bf[kk] = wp[base + kk * 64];
    int cout = nt * 16 + l16;
    float pb = proj_bias[cout];
#pragma unroll
    for (int mt = 0; mt < 4; mt++) {
      f32x4 acc = {0.f, 0.f, 0.f, 0.f};
#pragma unroll
      for (int kk = 0; kk < 6; kk++) {
        s16x8 a = *(const s16x8*)&ao[(mt * 16 + l16) * AO_S + kk * 32 + quad * 8];
        acc = __builtin_amdgcn_mfma_f32_16x16x32_bf16(a, bf[kk], acc, 0, 0, 0);
      }
      int t0 = mt * 16 + quad * 4;
#pragma unroll
      for (int r = 0; r < 4; r++) {
        int t = t0 + r;
        if (t < NTOK) {
          int i = t / 7, j = t % 7;
          int R = wr * 7 + i + 3;  if (R >= H_DIM) R -= H_DIM;
          int Cc = wc * 7 + j + 3; if (Cc >= W_DIM) Cc -= W_DIM;
          out[cout * HW + R * W_DIM + Cc] = acc[r] + pb;
        }
      }
    }
  }
}

// ---------------------------------------------------------------------------
extern "C" void kernel_launch(void* const* d_in, const int* in_sizes, int n_in,
                              void* d_out, int out_size, void* d_ws, size_t ws_size,
                              hipStream_t stream) {
  const float* x     = (const float*)d_in[0];
  const float* wqkv  = (const float*)d_in[1];
  const float* bqkv  = (const float*)d_in[2];
  const float* wproj = (const float*)d_in[3];
  const float* bproj = (const float*)d_in[4];
  const float* table = (const float*)d_in[5];

  unsigned short* wqkv_p = (unsigned short*)d_ws;            // 110592 bf16
  unsigned short* wproj_p = wqkv_p + 110592;                 // 36864 bf16
  float* biasM = (float*)(wproj_p + 36864);                  // 24576 f32

  pack_wqkv<<<54, 256, 0, stream>>>(wqkv, wqkv_p);
  pack_wproj<<<18, 256, 0, stream>>>(wproj, wproj_p);
  bias_prep<<<96, 256, 0, stream>>>(table, biasM);
  swin_fused<<<4096, 256, 0, stream>>>(x, bqkv, bproj, wqkv_p, wproj_p, biasM,
                                       (float*)d_out);
}

// Round 2
// 583.644 us; speedup vs baseline: 1.1046x; 1.1046x over previous
//
#include <hip/hip_runtime.h>

// ---------------------------------------------------------------------------
// Shifted Window Attention, 3-pass: transpose-in -> fused per-window attn ->
// transpose-out. bf16 MFMA 16x16x32.
// C=192, H=W=448, window 7x7 (N=49 pad 64), shift 3, NH=6, hd=32, nW=4096.
// ---------------------------------------------------------------------------

typedef short s16x8 __attribute__((ext_vector_type(8)));   // 8 bf16 (4 VGPRs)
typedef float f32x4 __attribute__((ext_vector_type(4)));
typedef unsigned short u16x4 __attribute__((ext_vector_type(4)));

#define C_DIM 192
#define H_DIM 448
#define W_DIM 448
#define HW    (H_DIM * W_DIM)   // 200704
#define NHEAD 6
#define NTOK  49
#define MT    64                // padded token count

// LDS strides in bf16 elements
#define XW_S 200                // 25 16B-chunks per token row (24 data + 1 pad)
#define AO_S 200
#define QH_S 40
#define KH_S 40
#define VT_S 72
#define PH_S 72

__device__ __forceinline__ unsigned short f2bf(float f) {
  unsigned u = __float_as_uint(f);
  u = (u + 0x7fffu + ((u >> 16) & 1u)) >> 16;   // RNE
  return (unsigned short)u;
}

__device__ __forceinline__ void gl_lds16(const void* g, void* l) {
  __builtin_amdgcn_global_load_lds(
      (const __attribute__((address_space(1))) void*)g,
      (__attribute__((address_space(3))) void*)l, 16, 0, 0);
}

// ---- prep: pack qkv_weight (576x192 f32) into B-fragment order, bf16 -------
__global__ void pack_wqkv(const float* __restrict__ w, unsigned short* __restrict__ dst) {
  int g = blockIdx.x * blockDim.x + threadIdx.x;
  if (g >= 13824) return;
  int lane = g & 63;
  int t1 = g >> 6;
  int kk = t1 % 6;  t1 /= 6;
  int dt = t1 & 1;  t1 >>= 1;
  int which = t1 % 3;
  int h = t1 / 3;
  int n  = which * 192 + h * 32 + dt * 16 + (lane & 15);
  int kb = kk * 32 + (lane >> 4) * 8;
  const float* src = w + n * 192 + kb;
  unsigned short* d = dst + g * 8;
#pragma unroll
  for (int j = 0; j < 8; j++) d[j] = f2bf(src[j]);
}

// ---- prep: pack proj_weight (192x192) -------------------------------------
__global__ void pack_wproj(const float* __restrict__ w, unsigned short* __restrict__ dst) {
  int g = blockIdx.x * blockDim.x + threadIdx.x;
  if (g >= 4608) return;
  int lane = g & 63;
  int t1 = g >> 6;
  int kk = t1 % 6;
  int nt = t1 / 6;
  int n  = nt * 16 + (lane & 15);
  int kb = kk * 32 + (lane >> 4) * 8;
  const float* src = w + n * 192 + kb;
  unsigned short* d = dst + g * 8;
#pragma unroll
  for (int j = 0; j < 8; j++) d[j] = f2bf(src[j]);
}

// ---- prep: relative-position bias -> [6][64][64] f32, zero-padded ---------
__global__ void bias_prep(const float* __restrict__ table, float* __restrict__ dst) {
  int t = blockIdx.x * blockDim.x + threadIdx.x;
  if (t >= 6 * 64 * 64) return;
  int j = t & 63;
  int i = (t >> 6) & 63;
  int h = t >> 12;
  float v = 0.f;
  if (i < NTOK && j < NTOK) {
    int s = (i / 7 - j / 7) + (i % 7 - j % 7);
    if (s < 0) s += 169;
    v = table[s * 6 + h];
  }
  dst[t] = v;
}

// ---- Pass A: x (C,H,W) f32 -> xT rolled (H*W, C) bf16 ---------------------
// Tile: 64 hw-cols x 192 c. Read coalesced along hw, write coalesced along c.
__global__ __launch_bounds__(256) void transpose_in(
    const float* __restrict__ x, unsigned short* __restrict__ xT) {
  __shared__ __align__(16) unsigned short tile[64 * XW_S];
  const int hw0 = blockIdx.x * 64;
  const int col = threadIdx.x & 63;
  const int hw = hw0 + col;
#pragma unroll 8
  for (int c = threadIdx.x >> 6; c < 192; c += 4)
    tile[col * XW_S + c] = f2bf(x[c * HW + hw]);
  __syncthreads();
  const int r = hw0 / W_DIM;
  const int wbase = hw0 % W_DIM;
  int rp = r + (H_DIM - 3); if (rp >= H_DIM) rp -= H_DIM;
  for (int t = threadIdx.x; t < 64 * 24; t += 256) {
    int cc = t / 24, c8 = t % 24;
    int w = wbase + cc;
    int wp = w + (W_DIM - 3); if (wp >= W_DIM) wp -= W_DIM;
    *(s16x8*)(xT + ((rp * W_DIM + wp) * 192 + c8 * 8)) =
        *(const s16x8*)&tile[cc * XW_S + c8 * 8];
  }
}

// ---- Pass C: outT (H*W, C) -> out (C,H,W) f32 -----------------------------
// MODE 0: outT is f32; MODE 1: outT is bf16.
template <int MODE>
__global__ __launch_bounds__(256) void transpose_out(
    const void* __restrict__ oT, float* __restrict__ out) {
  __shared__ __align__(16) float tile[64 * 196];
  const int hw0 = blockIdx.x * 64;
  if (MODE == 0) {
    const float* p = (const float*)oT;
    for (int t = threadIdx.x; t < 64 * 48; t += 256) {
      int cc = t / 48, c4 = t % 48;
      *(f32x4*)&tile[cc * 196 + c4 * 4] =
          *(const f32x4*)(p + (hw0 + cc) * 192 + c4 * 4);
    }
  } else {
    const unsigned short* p = (const unsigned short*)oT;
    for (int t = threadIdx.x; t < 64 * 24; t += 256) {
      int cc = t / 24, c8 = t % 24;
      s16x8 v = *(const s16x8*)(p + (hw0 + cc) * 192 + c8 * 8);
#pragma unroll
      for (int k = 0; k < 8; k++)
        tile[cc * 196 + c8 * 8 + k] =
            __uint_as_float(((unsigned)(unsigned short)v[k]) << 16);
    }
  }
  __syncthreads();
  const int col = threadIdx.x & 63;
#pragma unroll 8
  for (int c = threadIdx.x >> 6; c < 192; c += 4)
    out[c * HW + hw0 + col] = tile[col * 196 + c];
}

// ---------------------------------------------------------------------------
// MODE 0: stage from xT, write outT f32   MODE 1: stage from xT, write outT bf16
// MODE 2: stage from xT, scatter f32 to out (C,H,W)
// MODE 3: stage from x (round-1 path), scatter to out
template <int MODE>
__global__ __launch_bounds__(256, 2) void swin_fused(
    const float* __restrict__ x,
    const unsigned short* __restrict__ xT,
    const float* __restrict__ qkv_bias,
    const float* __restrict__ proj_bias,
    const unsigned short* __restrict__ wqkv_p,
    const unsigned short* __restrict__ wproj_p,
    const float* __restrict__ biasM,     // [6][64][64] f32
    void* __restrict__ outT,
    float* __restrict__ out) {
  __shared__ __align__(16) unsigned short xw[MT * XW_S];   // tokens x C (bf16)
  __shared__ __align__(16) unsigned short ao[MT * AO_S];   // attn out tokens x C
  __shared__ __align__(16) unsigned short qh[MT * QH_S];   // per-head q 64x32
  __shared__ __align__(16) unsigned short kh[MT * KH_S];   // per-head k 64x32
  __shared__ __align__(16) unsigned short vth[32 * VT_S];  // per-head v^T 32x64
  __shared__ __align__(16) unsigned short Ph[MT * PH_S];   // per-head P 64x64
  __shared__ int mreg[MT];

  const int tid  = threadIdx.x;
  const int lane = tid & 63;
  const int wid  = tid >> 6;
  const int l16  = lane & 15;
  const int quad = lane >> 4;
  const int wr   = blockIdx.x >> 6;
  const int wc   = blockIdx.x & 63;

  // ---- Phase 0: stage window into LDS ------------------------------------
  if (MODE != 3) {
    // xT is rolled token-major bf16. 49 tokens x 25 chunks (24 data + 1 pad)
    // so the LDS destination is exactly wave-linear at stride XW_S=200.
    const unsigned short* xTw = xT + ((wr * 7) * W_DIM + wc * 7) * 192;
    for (int base = wid * 64; base < 1225; base += 256) {
      int t = base + lane;
      if (t < 1225) {
        int tok = t / 25, c8 = t % 25;
        int i = tok / 7, j = tok % 7;
        const unsigned short* g =
            (c8 == 24) ? xTw : xTw + (i * W_DIM + j) * 192 + c8 * 8;
        gl_lds16(g, &xw[base * 8]);
      }
    }
    // zero rows 49..63 (chunks 1225..1599)
    s16x8 zz = {0, 0, 0, 0, 0, 0, 0, 0};
    for (int idx = tid; idx < 375; idx += 256)
      *(s16x8*)&xw[(1225 + idx) * 8] = zz;
  } else {
    for (int task = tid; task < 1344; task += 256) {      // (c,i): 192*7
      int c = task / 7;
      int i = task % 7;
      int r = wr * 7 + i + 3; if (r >= H_DIM) r -= H_DIM;
      const float* src = x + c * HW + r * W_DIM;
      int cb = wc * 7 + 3;
#pragma unroll
      for (int j = 0; j < 7; j++) {
        int w = cb + j; if (w >= W_DIM) w -= W_DIM;
        xw[(i * 7 + j) * XW_S + c] = f2bf(src[w]);
      }
    }
    for (int idx = tid; idx < 15 * C_DIM; idx += 256)
      xw[(NTOK + idx / C_DIM) * XW_S + (idx % C_DIM)] = 0;
  }
  if (tid < MT) {
    int v = 99;                                          // distinct for pads
    if (tid < NTOK) {
      int gi = wr * 7 + tid / 7, gj = wc * 7 + tid % 7;
      int rb = (gi >= 441) + (gi >= 445);
      int cb = (gj >= 441) + (gj >= 445);
      v = rb * 3 + cb;
    }
    mreg[tid] = v;
  }
  __syncthreads();

  const float scale = 0.17677669529663687f;   // 32^-0.5

  for (int h = 0; h < NHEAD; h++) {
    // ---- H1: per-head qkv chunk gemm (64x96, K=192) ----------------------
    for (int e = wid; e < 6; e += 4) {
      int which = e >> 1;   // 0=q 1=k 2=v
      int dt = e & 1;
      s16x8 bf[6];
      const s16x8* wp = (const s16x8*)wqkv_p;
      int base = (((h * 3 + which) * 2 + dt) * 6) * 64 + lane;
#pragma unroll
      for (int kk = 0; kk < 6; kk++) bf[kk] = wp[base + kk * 64];
      int ncol = which * 192 + h * 32 + dt * 16 + l16;
      float bias = qkv_bias[ncol];
      int dl = dt * 16 + l16;
#pragma unroll
      for (int mt = 0; mt < 4; mt++) {
        f32x4 acc = {0.f, 0.f, 0.f, 0.f};
#pragma unroll
        for (int kk = 0; kk < 6; kk++) {
          s16x8 a = *(const s16x8*)&xw[(mt * 16 + l16) * XW_S + kk * 32 + quad * 8];
          acc = __builtin_amdgcn_mfma_f32_16x16x32_bf16(a, bf[kk], acc, 0, 0, 0);
        }
        int t0 = mt * 16 + quad * 4;
        if (which == 0) {
#pragma unroll
          for (int r = 0; r < 4; r++) qh[(t0 + r) * QH_S + dl] = f2bf(acc[r] + bias);
        } else if (which == 1) {
#pragma unroll
          for (int r = 0; r < 4; r++) kh[(t0 + r) * KH_S + dl] = f2bf(acc[r] + bias);
        } else {
          u16x4 pv;
#pragma unroll
          for (int r = 0; r < 4; r++) pv[r] = f2bf(acc[r] + bias);
          *(u16x4*)&vth[dl * VT_S + t0] = pv;        // transposed store
        }
      }
    }
    __syncthreads();

    // ---- H2: scores + softmax (wave owns m-tile = wid) -------------------
    {
      const int mt = wid;
      s16x8 aq = *(const s16x8*)&qh[(mt * 16 + l16) * QH_S + quad * 8];
      f32x4 sc[4];
#pragma unroll
      for (int nt = 0; nt < 4; nt++) {
        s16x8 bk = *(const s16x8*)&kh[(nt * 16 + l16) * KH_S + quad * 8];
        f32x4 z = {0.f, 0.f, 0.f, 0.f};
        sc[nt] = __builtin_amdgcn_mfma_f32_16x16x32_bf16(aq, bk, z, 0, 0, 0);
      }
      float sv[4][4];   // [r][nt]
#pragma unroll
      for (int nt = 0; nt < 4; nt++) {
        int j = nt * 16 + l16;
        int mj = mreg[j];
        float mpad = (j >= NTOK) ? -30000.f : 0.f;
#pragma unroll
        for (int r = 0; r < 4; r++) {
          int i = mt * 16 + quad * 4 + r;
          float s = sc[nt][r] * scale + biasM[(h * 64 + i) * 64 + j];
          s += (mreg[i] == mj) ? 0.f : -100.f;
          sv[r][nt] = s + mpad;
        }
      }
#pragma unroll
      for (int r = 0; r < 4; r++) {
        float mx = fmaxf(fmaxf(sv[r][0], sv[r][1]), fmaxf(sv[r][2], sv[r][3]));
#pragma unroll
        for (int off = 1; off < 16; off <<= 1) mx = fmaxf(mx, __shfl_xor(mx, off));
        float e0 = __expf(sv[r][0] - mx), e1 = __expf(sv[r][1] - mx);
        float e2 = __expf(sv[r][2] - mx), e3 = __expf(sv[r][3] - mx);
        float sm = e0 + e1 + e2 + e3;
#pragma unroll
        for (int off = 1; off < 16; off <<= 1) sm += __shfl_xor(sm, off);
        float inv = 1.f / sm;
        int i = mt * 16 + quad * 4 + r;
        Ph[i * PH_S +  0 + l16] = f2bf(e0 * inv);
        Ph[i * PH_S + 16 + l16] = f2bf(e1 * inv);
        Ph[i * PH_S + 32 + l16] = f2bf(e2 * inv);
        Ph[i * PH_S + 48 + l16] = f2bf(e3 * inv);
      }
    }
    // No barrier: wave w wrote Ph rows [w*16,w*16+16) and reads only those.

    // ---- H3: PV (wave owns m-tile = wid) ---------------------------------
    {
      const int mt = wid;
      s16x8 ap0 = *(const s16x8*)&Ph[(mt * 16 + l16) * PH_S + quad * 8];
      s16x8 ap1 = *(const s16x8*)&Ph[(mt * 16 + l16) * PH_S + 32 + quad * 8];
#pragma unroll
      for (int dtv = 0; dtv < 2; dtv++) {
        s16x8 bv0 = *(const s16x8*)&vth[(dtv * 16 + l16) * VT_S + quad * 8];
        s16x8 bv1 = *(const s16x8*)&vth[(dtv * 16 + l16) * VT_S + 32 + quad * 8];
        f32x4 acc = {0.f, 0.f, 0.f, 0.f};
        acc = __builtin_amdgcn_mfma_f32_16x16x32_bf16(ap0, bv0, acc, 0, 0, 0);
        acc = __builtin_amdgcn_mfma_f32_16x16x32_bf16(ap1, bv1, acc, 0, 0, 0);
        int t0 = mt * 16 + quad * 4;
#pragma unroll
        for (int r = 0; r < 4; r++)
          ao[(t0 + r) * AO_S + h * 32 + dtv * 16 + l16] = f2bf(acc[r]);
      }
    }
    __syncthreads();   // protects qh/kh/vth reuse next head, ao for proj
  }

  // ---- Proj (64x192, K=192) + store ---------------------------------------
  for (int nt = wid; nt < 12; nt += 4) {
    s16x8 bf[6];
    const s16x8* wp = (const s16x8*)wproj_p;
    int base = nt * 6 * 64 + lane;
#pragma unroll
    for (int kk = 0; kk < 6; kk++) bf[kk] = wp[base + kk * 64];
    int cout = nt * 16 + l16;
    float pb = proj_bias[cout];
#pragma unroll
    for (int mt = 0; mt < 4; mt++) {
      f32x4 acc = {0.f, 0.f, 0.f, 0.f};
#pragma unroll
      for (int kk = 0; kk < 6; kk++) {
        s16x8 a = *(const s16x8*)&ao[(mt * 16 + l16) * AO_S + kk * 32 + quad * 8];
        acc = __builtin_amdgcn_mfma_f32_16x16x32_bf16(a, bf[kk], acc, 0, 0, 0);
      }
      int t0 = mt * 16 + quad * 4;
#pragma unroll
      for (int r = 0; r < 4; r++) {
        int t = t0 + r;
        if (t < NTOK) {
          int i = t / 7, j = t % 7;
          int R = wr * 7 + i + 3;  if (R >= H_DIM) R -= H_DIM;
          int Cc = wc * 7 + j + 3; if (Cc >= W_DIM) Cc -= W_DIM;
          float v = acc[r] + pb;
          if (MODE == 2 || MODE == 3) {
            out[cout * HW + R * W_DIM + Cc] = v;
          } else if (MODE == 0) {
            ((float*)outT)[(R * W_DIM + Cc) * 192 + cout] = v;
          } else {
            ((unsigned short*)outT)[(R * W_DIM + Cc) * 192 + cout] = f2bf(v);
          }
        }
      }
    }
  }
}

// ---------------------------------------------------------------------------
extern "C" void kernel_launch(void* const* d_in, const int* in_sizes, int n_in,
                              void* d_out, int out_size, void* d_ws, size_t ws_size,
                              hipStream_t stream) {
  const float* x     = (const float*)d_in[0];
  const float* wqkv  = (const float*)d_in[1];
  const float* bqkv  = (const float*)d_in[2];
  const float* wproj = (const float*)d_in[3];
  const float* bproj = (const float*)d_in[4];
  const float* table = (const float*)d_in[5];
  float* out = (float*)d_out;

  unsigned short* wqkv_p = (unsigned short*)d_ws;            // 110592 bf16
  unsigned short* wproj_p = wqkv_p + 110592;                 // 36864 bf16
  float* biasM = (float*)(wproj_p + 36864);                  // 24576 f32
  const size_t base_b = 393216;                              // = above, exact
  const size_t xT_b = (size_t)HW * 192 * 2;                  // 77,070,336
  const size_t oT32_b = (size_t)HW * 192 * 4;
  unsigned short* xT = (unsigned short*)((char*)d_ws + base_b);
  void* outT = (char*)d_ws + base_b + xT_b;

  int mode;
  if (ws_size >= base_b + xT_b + oT32_b) mode = 0;
  else if (ws_size >= base_b + xT_b + xT_b) mode = 1;
  else if (ws_size >= base_b + xT_b) mode = 2;
  else mode = 3;

  pack_wqkv<<<54, 256, 0, stream>>>(wqkv, wqkv_p);
  pack_wproj<<<18, 256, 0, stream>>>(wproj, wproj_p);
  bias_prep<<<96, 256, 0, stream>>>(table, biasM);
  if (mode != 3)
    transpose_in<<<HW / 64, 256, 0, stream>>>(x, xT);

  switch (mode) {
    case 0:
      swin_fused<0><<<4096, 256, 0, stream>>>(x, xT, bqkv, bproj, wqkv_p,
                                              wproj_p, biasM, outT, out);
      transpose_out<0><<<HW / 64, 256, 0, stream>>>(outT, out);
      break;
    case 1:
      swin_fused<1><<<4096, 256, 0, stream>>>(x, xT, bqkv, bproj, wqkv_p,
                                              wproj_p, biasM, outT, out);
      transpose_out<1><<<HW / 64, 256, 0, stream>>>(outT, out);
      break;
    case 2:
      swin_fused<2><<<4096, 256, 0, stream>>>(x, xT, bqkv, bproj, wqkv_p,
                                              wproj_p, biasM, outT, out);
      break;
    default:
      swin_fused<3><<<4096, 256, 0, stream>>>(x, xT, bqkv, bproj, wqkv_p,
                                              wproj_p, biasM, outT, out);
      break;
  }
}

// Round 3
// 542.079 us; speedup vs baseline: 1.1893x; 1.0767x over previous
//
#include <hip/hip_runtime.h>

// ---------------------------------------------------------------------------
// Shifted Window Attention, 3-pass: transpose-in -> fused per-window attn ->
// transpose-out. bf16 MFMA 16x16x32.
// C=192, H=W=448, window 7x7 (N=49 pad 64), shift 3, NH=6, hd=32, nW=4096.
// ---------------------------------------------------------------------------

typedef short s16x8 __attribute__((ext_vector_type(8)));   // 8 bf16 (4 VGPRs)
typedef float f32x4 __attribute__((ext_vector_type(4)));
typedef unsigned short u16x4 __attribute__((ext_vector_type(4)));

#define C_DIM 192
#define H_DIM 448
#define W_DIM 448
#define HW    (H_DIM * W_DIM)   // 200704
#define NHEAD 6
#define NTOK  49
#define MT    64                // padded token count
#define QSCALE 0.17677669529663687f

// LDS strides in bf16 elements
#define XW_S 200                // 25 16B-chunks per token row (24 data + 1 pad)
#define AO_S 200
#define QH_S 40
#define KH_S 40
#define VT_S 72
#define PH_S 72

__device__ __forceinline__ unsigned short f2bf(float f) {
  unsigned u = __float_as_uint(f);
  u = (u + 0x7fffu + ((u >> 16) & 1u)) >> 16;   // RNE
  return (unsigned short)u;
}

__device__ __forceinline__ void gl_lds16(const void* g, void* l) {
  __builtin_amdgcn_global_load_lds(
      (const __attribute__((address_space(1))) void*)g,
      (__attribute__((address_space(3))) void*)l, 16, 0, 0);
}

// ---- prep: pack qkv_weight (576x192 f32) into B-fragment order, bf16 -------
// q rows (which==0) pre-scaled by hd^-0.5 so H2 needs no scale multiply.
__global__ void pack_wqkv(const float* __restrict__ w, unsigned short* __restrict__ dst) {
  int g = blockIdx.x * blockDim.x + threadIdx.x;
  if (g >= 13824) return;
  int lane = g & 63;
  int t1 = g >> 6;
  int kk = t1 % 6;  t1 /= 6;
  int dt = t1 & 1;  t1 >>= 1;
  int which = t1 % 3;
  int h = t1 / 3;
  int n  = which * 192 + h * 32 + dt * 16 + (lane & 15);
  int kb = kk * 32 + (lane >> 4) * 8;
  const float* src = w + n * 192 + kb;
  unsigned short* d = dst + g * 8;
  float m = (which == 0) ? QSCALE : 1.f;
#pragma unroll
  for (int j = 0; j < 8; j++) d[j] = f2bf(src[j] * m);
}

// ---- prep: pack proj_weight (192x192) -------------------------------------
__global__ void pack_wproj(const float* __restrict__ w, unsigned short* __restrict__ dst) {
  int g = blockIdx.x * blockDim.x + threadIdx.x;
  if (g >= 4608) return;
  int lane = g & 63;
  int t1 = g >> 6;
  int kk = t1 % 6;
  int nt = t1 / 6;
  int n  = nt * 16 + (lane & 15);
  int kb = kk * 32 + (lane >> 4) * 8;
  const float* src = w + n * 192 + kb;
  unsigned short* d = dst + g * 8;
#pragma unroll
  for (int j = 0; j < 8; j++) d[j] = f2bf(src[j]);
}

// ---- prep: relative-position bias -> [6][64][64] f32 ----------------------
// j>=49 baked to -30000 (pad keys); i>=49, j<49 -> 0 (keeps pad-row softmax
// finite for interior windows). Negative rel-index wraps (+169) per reference.
__global__ void bias_prep(const float* __restrict__ table, float* __restrict__ dst) {
  int t = blockIdx.x * blockDim.x + threadIdx.x;
  if (t >= 6 * 64 * 64) return;
  int j = t & 63;
  int i = (t >> 6) & 63;
  int h = t >> 12;
  float v;
  if (j >= NTOK) v = -30000.f;
  else if (i >= NTOK) v = 0.f;
  else {
    int s = (i / 7 - j / 7) + (i % 7 - j % 7);
    if (s < 0) s += 169;
    v = table[s * 6 + h];
  }
  dst[t] = v;
}

// ---- Pass A: x (C,H,W) f32 -> xT rolled (H*W, C) bf16 ---------------------
// 128-hw tile; f32x4 reads (512B contiguous per half-wave); rotated-chunk LDS
// layout keeps write phase on ds_read_b128; writes are dense 384B per token.
__global__ __launch_bounds__(256) void transpose_in(
    const float* __restrict__ x, unsigned short* __restrict__ xT) {
  __shared__ __align__(16) unsigned short tile[128 * 200];
  const int hw0 = blockIdx.x * 128;
  for (int u = threadIdx.x; u < 192 * 32; u += 256) {
    int c = u >> 5, l32 = u & 31;
    int hl = l32 * 4;
    f32x4 v = *(const f32x4*)(x + (size_t)c * HW + hw0 + hl);
    int c8 = c >> 3, o = c & 7;
#pragma unroll
    for (int i = 0; i < 4; i++) {
      int hh = hl + i;
      int rot = c8 + hh; rot %= 25;
      tile[hh * 200 + rot * 8 + o] = f2bf(v[i]);
    }
  }
  __syncthreads();
  for (int u = threadIdx.x; u < 128 * 24; u += 256) {
    int t = u / 24, k = u % 24;
    int hw = hw0 + t;
    int r = hw / W_DIM, w = hw - r * W_DIM;
    int rp = r + (H_DIM - 3); if (rp >= H_DIM) rp -= H_DIM;
    int wp = w + (W_DIM - 3); if (wp >= W_DIM) wp -= W_DIM;
    int rot = k + t; rot %= 25;
    *(s16x8*)(xT + ((size_t)(rp * W_DIM + wp) * 192 + k * 8)) =
        *(const s16x8*)&tile[t * 200 + rot * 8];
  }
}

// ---- Pass C: outT (H*W, C) f32 -> out (C,H,W) f32 -------------------------
__global__ __launch_bounds__(256) void transpose_out(
    const float* __restrict__ oT, float* __restrict__ out) {
  __shared__ __align__(16) float tile[64 * 196];
  const int hw0 = blockIdx.x * 64;
  for (int t = threadIdx.x; t < 64 * 48; t += 256) {
    int cc = t / 48, c4 = t % 48;
    *(f32x4*)&tile[cc * 196 + c4 * 4] =
        *(const f32x4*)(oT + (size_t)(hw0 + cc) * 192 + c4 * 4);
  }
  __syncthreads();
  const int col = threadIdx.x & 63;
#pragma unroll 8
  for (int c = threadIdx.x >> 6; c < 192; c += 4)
    out[(size_t)c * HW + hw0 + col] = tile[col * 196 + c];
}

// ---------------------------------------------------------------------------
// MODE 0: stage from xT, write outT f32
// MODE 2: stage from xT, scatter f32 to out (C,H,W)
// MODE 3: stage from x directly, scatter to out
template <int MODE>
__global__ __launch_bounds__(256, 2) void swin_fused(
    const float* __restrict__ x,
    const unsigned short* __restrict__ xT,
    const float* __restrict__ qkv_bias,
    const float* __restrict__ proj_bias,
    const unsigned short* __restrict__ wqkv_p,
    const unsigned short* __restrict__ wproj_p,
    const float* __restrict__ biasM,     // [6][64][64] f32
    float* __restrict__ outT,
    float* __restrict__ out) {
  __shared__ __align__(16) unsigned short xw[MT * XW_S];   // tokens x C (bf16)
  __shared__ __align__(16) unsigned short ao[MT * AO_S];   // attn out tokens x C
  __shared__ __align__(16) unsigned short qh[MT * QH_S];   // per-head q 64x32
  __shared__ __align__(16) unsigned short kh[MT * KH_S];   // per-head k 64x32
  __shared__ __align__(16) unsigned short vth[32 * VT_S];  // per-head v^T 32x64
  __shared__ __align__(16) unsigned short Ph[MT * PH_S];   // per-head P 64x64
  __shared__ int mreg[MT];

  const int tid  = threadIdx.x;
  const int lane = tid & 63;
  const int wid  = tid >> 6;
  const int l16  = lane & 15;
  const int quad = lane >> 4;
  // XCD-contiguous swizzle: each XCD (blk%8) gets 8 contiguous window-rows.
  const int wix  = ((blockIdx.x & 7) << 9) | (blockIdx.x >> 3);
  const int wr   = wix >> 6;
  const int wc   = wix & 63;
  const bool edge = (wr == 63) || (wc == 63);

  // ---- Phase 0: stage window into LDS ------------------------------------
  if (MODE != 3) {
    const unsigned short* xTw = xT + ((size_t)(wr * 7) * W_DIM + wc * 7) * 192;
    for (int base = wid * 64; base < 1225; base += 256) {
      int t = base + lane;
      if (t < 1225) {
        int tok = t / 25, c8 = t % 25;
        int i = tok / 7, j = tok % 7;
        const unsigned short* g =
            (c8 == 24) ? xTw : xTw + ((size_t)(i * W_DIM + j)) * 192 + c8 * 8;
        gl_lds16(g, &xw[base * 8]);
      }
    }
    s16x8 zz = {0, 0, 0, 0, 0, 0, 0, 0};
    for (int idx = tid; idx < 375; idx += 256)
      *(s16x8*)&xw[(1225 + idx) * 8] = zz;
  } else {
    for (int task = tid; task < 1344; task += 256) {
      int c = task / 7;
      int i = task % 7;
      int r = wr * 7 + i + 3; if (r >= H_DIM) r -= H_DIM;
      const float* src = x + (size_t)c * HW + r * W_DIM;
      int cb = wc * 7 + 3;
#pragma unroll
      for (int j = 0; j < 7; j++) {
        int w = cb + j; if (w >= W_DIM) w -= W_DIM;
        xw[(i * 7 + j) * XW_S + c] = f2bf(src[w]);
      }
    }
    for (int idx = tid; idx < 15 * C_DIM; idx += 256)
      xw[(NTOK + idx / C_DIM) * XW_S + (idx % C_DIM)] = 0;
  }
  if (tid < MT) {
    int v = 99;
    if (tid < NTOK) {
      int gi = wr * 7 + tid / 7, gj = wc * 7 + tid % 7;
      int rb = (gi >= 441) + (gi >= 445);
      int cb = (gj >= 441) + (gj >= 445);
      v = rb * 3 + cb;
    }
    mreg[tid] = v;
  }
  __syncthreads();

  // H1 work split: 24 (e,mt) units over 4 waves, 6 each -> 36 MFMA/wave.
  // Wave covers e in {eA,eB}: mt range mtA0..3 for eA, 0..cntB-1 for eB.
  const int ubase = wid * 6;
  const int eA = ubase >> 2, mtA0 = ubase & 3;
  const int cntA = 4 - mtA0;
  const int eB = eA + 1, cntB = 6 - cntA;

  for (int h = 0; h < NHEAD; h++) {
    // ---- H1: per-head qkv chunk gemm (64x96, K=192), balanced ------------
    {
      const s16x8* wp = (const s16x8*)wqkv_p;
      s16x8 bfA[6], bfB[6];
      const int whA = eA >> 1, dtA = eA & 1;
      const int whB = eB >> 1, dtB = eB & 1;
      const int baseA = (((h * 3 + whA) * 2 + dtA) * 6) * 64 + lane;
      const int baseB = (((h * 3 + whB) * 2 + dtB) * 6) * 64 + lane;
#pragma unroll
      for (int kk = 0; kk < 6; kk++) {
        bfA[kk] = wp[baseA + kk * 64];
        bfB[kk] = wp[baseB + kk * 64];
      }
      float biasA = qkv_bias[whA * 192 + h * 32 + dtA * 16 + l16];
      float biasB = qkv_bias[whB * 192 + h * 32 + dtB * 16 + l16];
      if (whA == 0) biasA *= QSCALE;
      if (whB == 0) biasB *= QSCALE;

#pragma unroll
      for (int mt = 0; mt < 4; mt++) {
        const bool inA = (mt >= mtA0);
        const bool inB = (mt < cntB);
        s16x8 a[6];
#pragma unroll
        for (int kk = 0; kk < 6; kk++)
          a[kk] = *(const s16x8*)&xw[(mt * 16 + l16) * XW_S + kk * 32 + quad * 8];
        const int t0 = mt * 16 + quad * 4;
        if (inA) {
          f32x4 acc = {0.f, 0.f, 0.f, 0.f};
#pragma unroll
          for (int kk = 0; kk < 6; kk++)
            acc = __builtin_amdgcn_mfma_f32_16x16x32_bf16(a[kk], bfA[kk], acc, 0, 0, 0);
          const int dl = dtA * 16 + l16;
          if (whA == 0) {
#pragma unroll
            for (int r = 0; r < 4; r++) qh[(t0 + r) * QH_S + dl] = f2bf(acc[r] + biasA);
          } else if (whA == 1) {
#pragma unroll
            for (int r = 0; r < 4; r++) kh[(t0 + r) * KH_S + dl] = f2bf(acc[r] + biasA);
          } else {
            u16x4 pv;
#pragma unroll
            for (int r = 0; r < 4; r++) pv[r] = f2bf(acc[r] + biasA);
            *(u16x4*)&vth[dl * VT_S + t0] = pv;
          }
        }
        if (inB) {
          f32x4 acc = {0.f, 0.f, 0.f, 0.f};
#pragma unroll
          for (int kk = 0; kk < 6; kk++)
            acc = __builtin_amdgcn_mfma_f32_16x16x32_bf16(a[kk], bfB[kk], acc, 0, 0, 0);
          const int dl = dtB * 16 + l16;
          if (whB == 0) {
#pragma unroll
            for (int r = 0; r < 4; r++) qh[(t0 + r) * QH_S + dl] = f2bf(acc[r] + biasB);
          } else if (whB == 1) {
#pragma unroll
            for (int r = 0; r < 4; r++) kh[(t0 + r) * KH_S + dl] = f2bf(acc[r] + biasB);
          } else {
            u16x4 pv;
#pragma unroll
            for (int r = 0; r < 4; r++) pv[r] = f2bf(acc[r] + biasB);
            *(u16x4*)&vth[dl * VT_S + t0] = pv;
          }
        }
      }
    }
    __syncthreads();

    // ---- H2: scores + softmax (wave owns m-tile = wid), no max-subtract --
    {
      const int mt = wid;
      // bias tile first (global loads overlap the MFMA below)
      const float* bMh = biasM + ((h * 64 + mt * 16 + quad * 4) * 64) + l16;
      float bm[4][4];   // [nt][r]
#pragma unroll
      for (int nt = 0; nt < 4; nt++)
#pragma unroll
        for (int r = 0; r < 4; r++) bm[nt][r] = bMh[r * 64 + nt * 16];

      s16x8 aq = *(const s16x8*)&qh[(mt * 16 + l16) * QH_S + quad * 8];
      f32x4 sc[4];
#pragma unroll
      for (int nt = 0; nt < 4; nt++) {
        s16x8 bk = *(const s16x8*)&kh[(nt * 16 + l16) * KH_S + quad * 8];
        f32x4 z = {0.f, 0.f, 0.f, 0.f};
        sc[nt] = __builtin_amdgcn_mfma_f32_16x16x32_bf16(aq, bk, z, 0, 0, 0);
      }
      if (edge) {
#pragma unroll
        for (int nt = 0; nt < 4; nt++) {
          int mj = mreg[nt * 16 + l16];
#pragma unroll
          for (int r = 0; r < 4; r++) {
            int i = mt * 16 + quad * 4 + r;
            bm[nt][r] += (mreg[i] == mj) ? 0.f : -100.f;
          }
        }
      }
#pragma unroll
      for (int r = 0; r < 4; r++) {
        float e0 = __expf(sc[0][r] + bm[0][r]);
        float e1 = __expf(sc[1][r] + bm[1][r]);
        float e2 = __expf(sc[2][r] + bm[2][r]);
        float e3 = __expf(sc[3][r] + bm[3][r]);
        float sm = (e0 + e1) + (e2 + e3);
#pragma unroll
        for (int off = 1; off < 16; off <<= 1) sm += __shfl_xor(sm, off);
        float inv = 1.f / sm;
        int i = mt * 16 + quad * 4 + r;
        Ph[i * PH_S +  0 + l16] = f2bf(e0 * inv);
        Ph[i * PH_S + 16 + l16] = f2bf(e1 * inv);
        Ph[i * PH_S + 32 + l16] = f2bf(e2 * inv);
        Ph[i * PH_S + 48 + l16] = f2bf(e3 * inv);
      }
    }
    // No barrier: wave w wrote Ph rows [w*16,w*16+16) and reads only those.

    // ---- H3: PV (wave owns m-tile = wid) ---------------------------------
    {
      const int mt = wid;
      s16x8 ap0 = *(const s16x8*)&Ph[(mt * 16 + l16) * PH_S + quad * 8];
      s16x8 ap1 = *(const s16x8*)&Ph[(mt * 16 + l16) * PH_S + 32 + quad * 8];
#pragma unroll
      for (int dtv = 0; dtv < 2; dtv++) {
        s16x8 bv0 = *(const s16x8*)&vth[(dtv * 16 + l16) * VT_S + quad * 8];
        s16x8 bv1 = *(const s16x8*)&vth[(dtv * 16 + l16) * VT_S + 32 + quad * 8];
        f32x4 acc = {0.f, 0.f, 0.f, 0.f};
        acc = __builtin_amdgcn_mfma_f32_16x16x32_bf16(ap0, bv0, acc, 0, 0, 0);
        acc = __builtin_amdgcn_mfma_f32_16x16x32_bf16(ap1, bv1, acc, 0, 0, 0);
        int t0 = mt * 16 + quad * 4;
#pragma unroll
        for (int r = 0; r < 4; r++)
          ao[(t0 + r) * AO_S + h * 32 + dtv * 16 + l16] = f2bf(acc[r]);
      }
    }
    __syncthreads();   // protects qh/kh/vth reuse next head, ao for proj
  }

  // ---- Proj (64x192, K=192) + store ---------------------------------------
  for (int nt = wid; nt < 12; nt += 4) {
    s16x8 bf[6];
    const s16x8* wp = (const s16x8*)wproj_p;
    int base = nt * 6 * 64 + lane;
#pragma unroll
    for (int kk = 0; kk < 6; kk++) bf[kk] = wp[base + kk * 64];
    int cout = nt * 16 + l16;
    float pb = proj_bias[cout];
#pragma unroll
    for (int mt = 0; mt < 4; mt++) {
      f32x4 acc = {0.f, 0.f, 0.f, 0.f};
#pragma unroll
      for (int kk = 0; kk < 6; kk++) {
        s16x8 a = *(const s16x8*)&ao[(mt * 16 + l16) * AO_S + kk * 32 + quad * 8];
        acc = __builtin_amdgcn_mfma_f32_16x16x32_bf16(a, bf[kk], acc, 0, 0, 0);
      }
      int t0 = mt * 16 + quad * 4;
#pragma unroll
      for (int r = 0; r < 4; r++) {
        int t = t0 + r;
        if (t < NTOK) {
          int i = t / 7, j = t % 7;
          int R = wr * 7 + i + 3;  if (R >= H_DIM) R -= H_DIM;
          int Cc = wc * 7 + j + 3; if (Cc >= W_DIM) Cc -= W_DIM;
          float v = acc[r] + pb;
          if (MODE == 0) {
            outT[(size_t)(R * W_DIM + Cc) * 192 + cout] = v;
          } else {
            out[(size_t)cout * HW + R * W_DIM + Cc] = v;
          }
        }
      }
    }
  }
}

// ---------------------------------------------------------------------------
extern "C" void kernel_launch(void* const* d_in, const int* in_sizes, int n_in,
                              void* d_out, int out_size, void* d_ws, size_t ws_size,
                              hipStream_t stream) {
  const float* x     = (const float*)d_in[0];
  const float* wqkv  = (const float*)d_in[1];
  const float* bqkv  = (const float*)d_in[2];
  const float* wproj = (const float*)d_in[3];
  const float* bproj = (const float*)d_in[4];
  const float* table = (const float*)d_in[5];
  float* out = (float*)d_out;

  unsigned short* wqkv_p = (unsigned short*)d_ws;            // 110592 bf16
  unsigned short* wproj_p = wqkv_p + 110592;                 // 36864 bf16
  float* biasM = (float*)(wproj_p + 36864);                  // 24576 f32
  const size_t base_b = 393216;
  const size_t xT_b = (size_t)HW * 192 * 2;                  // 77,070,336
  const size_t oT_b = (size_t)HW * 192 * 4;                  // 154,140,672
  unsigned short* xT = (unsigned short*)((char*)d_ws + base_b);
  float* outT = (float*)((char*)d_ws + base_b + xT_b);

  int mode;
  if (ws_size >= base_b + xT_b + oT_b) mode = 0;
  else if (ws_size >= base_b + xT_b) mode = 2;
  else mode = 3;

  pack_wqkv<<<54, 256, 0, stream>>>(wqkv, wqkv_p);
  pack_wproj<<<18, 256, 0, stream>>>(wproj, wproj_p);
  bias_prep<<<96, 256, 0, stream>>>(table, biasM);
  if (mode != 3)
    transpose_in<<<HW / 128, 256, 0, stream>>>(x, xT);

  switch (mode) {
    case 0:
      swin_fused<0><<<4096, 256, 0, stream>>>(x, xT, bqkv, bproj, wqkv_p,
                                              wproj_p, biasM, outT, out);
      transpose_out<<<HW / 64, 256, 0, stream>>>(outT, out);
      break;
    case 2:
      swin_fused<2><<<4096, 256, 0, stream>>>(x, xT, bqkv, bproj, wqkv_p,
                                              wproj_p, biasM, outT, out);
      break;
    default:
      swin_fused<3><<<4096, 256, 0, stream>>>(x, xT, bqkv, bproj, wqkv_p,
                                              wproj_p, biasM, outT, out);
      break;
  }
}